// Round 10
// baseline (424.924 us; speedup 1.0000x reference)
//
#include <hip/hip_runtime.h>
#include <hip/hip_cooperative_groups.h>
#include <math.h>

namespace cg = cooperative_groups;

// Sparse EdgeConvE round 10: cooperative mega-kernel, fixed launch
// (GRID=256, __launch_bounds__(256,2) caps VGPR<=256 so co-residency is
// guaranteed), with checked fallback to the r8 five-kernel path.
// Math identical to r8 (passed, absmax 5.9e-3).

#define NN 768
#define FF 64
#define DE 32
#define HH 64
#define EPB 32
#define GRID 256
#define CGRID 1024
#define ECAP (NN * 128)
#define SH1S 72

using bf16x8 = __attribute__((ext_vector_type(8))) short;
using f32x4  = __attribute__((ext_vector_type(4))) float;

__device__ __forceinline__ short f2b(float f) {
  unsigned u = __float_as_uint(f);
  return (short)((u + 0x7fffu + ((u >> 16) & 1u)) >> 16);   // RNE
}

// phase-B: H1[32x64]bf16 @ Wbp (B-frag packed) via 4 MFMA; run-length atomics.
// C/D layout: col=lane&15, row=(lane>>4)*4+reg.
__device__ __forceinline__ void phaseB_mfma(
    const short* sh1b, const int* si, const short* __restrict__ Wbp,
    const float* __restrict__ bb, float* __restrict__ xout,
    int lane, int wv, int nedge)
{
  const int q = lane >> 4, n = lane & 15;
  const int rt = wv >> 1;
  const int ctbase = (wv & 1) * 2;

  bf16x8 bf00 = *(const bf16x8*)(Wbp + ((((ctbase + 0) * 2 + 0) * 4 + q) * 16 + n) * 8);
  bf16x8 bf01 = *(const bf16x8*)(Wbp + ((((ctbase + 0) * 2 + 1) * 4 + q) * 16 + n) * 8);
  bf16x8 bf10 = *(const bf16x8*)(Wbp + ((((ctbase + 1) * 2 + 0) * 4 + q) * 16 + n) * 8);
  bf16x8 bf11 = *(const bf16x8*)(Wbp + ((((ctbase + 1) * 2 + 1) * 4 + q) * 16 + n) * 8);
  const float bias0 = bb[(ctbase + 0) * 16 + n];
  const float bias1 = bb[(ctbase + 1) * 16 + n];

  const short* sa = sh1b + (rt * 16 + n) * SH1S + q * 8;
  bf16x8 a0 = *(const bf16x8*)(sa);
  bf16x8 a1 = *(const bf16x8*)(sa + 32);

  f32x4 acc0 = {0.f, 0.f, 0.f, 0.f}, acc1 = {0.f, 0.f, 0.f, 0.f};
  acc0 = __builtin_amdgcn_mfma_f32_16x16x32_bf16(a0, bf00, acc0, 0, 0, 0);
  acc0 = __builtin_amdgcn_mfma_f32_16x16x32_bf16(a1, bf01, acc0, 0, 0, 0);
  acc1 = __builtin_amdgcn_mfma_f32_16x16x32_bf16(a0, bf10, acc1, 0, 0, 0);
  acc1 = __builtin_amdgcn_mfma_f32_16x16x32_bf16(a1, bf11, acc1, 0, 0, 0);

#pragma unroll
  for (int c2 = 0; c2 < 2; ++c2) {
    const f32x4 d = c2 ? acc1 : acc0;
    const float bias = c2 ? bias1 : bias0;
    const int ch = (ctbase + c2) * 16 + n;
    float sum = 0.0f;
    int cur = -1;
#pragma unroll
    for (int reg = 0; reg < 4; ++reg) {
      const int t = rt * 16 + q * 4 + reg;
      if (t < nedge) {
        const int it = si[t];
        const float v = fmaxf(d[reg] + bias, 0.0f);
        if (it != cur) {
          if (cur >= 0) atomicAdd(&xout[(cur << 6) + ch], sum);
          sum = 0.0f;
          cur = it;
        }
        sum += v;
      }
    }
    if (cur >= 0) atomicAdd(&xout[(cur << 6) + ch], sum);
  }
}

// ============================ cooperative path ============================
__global__ __launch_bounds__(256, 2) void mega_kernel(
    const float* __restrict__ A, const float* __restrict__ x,
    const float* __restrict__ e,
    const float* __restrict__ W1a, const float* __restrict__ b1a,
    const float* __restrict__ W1b, const float* __restrict__ b1b,
    const float* __restrict__ W2a, const float* __restrict__ b2a,
    const float* __restrict__ W2b, const float* __restrict__ b2b,
    const float* __restrict__ W3, const float* __restrict__ b3,
    const float* __restrict__ W4, const float* __restrict__ b4,
    float* __restrict__ out,
    int* gcnt, int* edges, float* x1, float* x2,
    float* U1, float* V1, float* U2, float* V2,
    float* ew2, short* Wbp1, short* Wbp2)
{
  cg::grid_group grid = cg::this_grid();
  const int tid = threadIdx.x, lane = tid & 63, wv = tid >> 6;
  const int bid = blockIdx.x;

  __shared__ int s_cnt, s_base;
  __shared__ int s_j[NN];
  __shared__ float sxr[64];
  __shared__ float su[4][64], sv[4][64];
  __shared__ __align__(16) short sh1b[EPB * SH1S];
  __shared__ int si[EPB];
  __shared__ float sred[4];

  // ========== phase 0: scan + U1/V1 + zero x1/x2 + pack Wb ==========
  for (int i = bid; i < NN; i += GRID) {
    __syncthreads();
    if (tid == 0) s_cnt = 0;
    __syncthreads();
    if (tid < 64) sxr[tid] = x[i * 64 + tid];
    for (int j = tid; j < NN; j += 256) {
      if (A[i * NN + j] != 0.0f) {
        int p = atomicAdd(&s_cnt, 1);
        s_j[p] = j;
      }
    }
    if (tid < 64) { x1[i * 64 + tid] = 0.0f; x2[i * 64 + tid] = 0.0f; }
    __syncthreads();
    {
      const int c = tid & 63, qr = tid >> 6;
      float u = 0.0f, v = 0.0f;
#pragma unroll
      for (int t = 0; t < 16; ++t) {
        const int d = qr * 16 + t;
        const float xv = sxr[d];
        const float wxi = W1a[d * 64 + c];
        const float wxj = W1a[(64 + d) * 64 + c];
        u = fmaf(xv, wxi - wxj, u);
        v = fmaf(xv, wxj, v);
      }
      su[qr][c] = u; sv[qr][c] = v;
    }
    if (tid == 0) s_base = atomicAdd(gcnt, s_cnt);
    __syncthreads();
    if (tid < 64) {
      U1[i * 64 + tid] = su[0][tid] + su[1][tid] + su[2][tid] + su[3][tid] + b1a[tid];
      V1[i * 64 + tid] = sv[0][tid] + sv[1][tid] + sv[2][tid] + sv[3][tid];
    }
    const int c = s_cnt, b = s_base;
    for (int t = tid; t < c; t += 256) edges[b + t] = (i << 10) | s_j[t];
  }
  if (bid < 2) {
    const float* src = (bid == 0) ? W1b : W2b;
    short* dst = (bid == 0) ? Wbp1 : Wbp2;
    for (int L = tid; L < 4096; L += 256) {
      const int j = L & 7, n = (L >> 3) & 15, quad = (L >> 7) & 3;
      const int kb = (L >> 9) & 1, ct = L >> 10;
      dst[L] = f2b(src[(kb * 32 + quad * 8 + j) * 64 + ct * 16 + n]);
    }
  }
  __threadfence();
  grid.sync();
  const int M = gcnt[0];

  // ========== phase 1: conv1 (+ ew2 side product) ==========
  {
    float w1e[DE], w2e[DE];
#pragma unroll
    for (int d = 0; d < DE; ++d) {
      w1e[d] = W1a[(128 + d) * HH + lane];
      w2e[d] = W2a[(128 + d) * HH + lane];
    }
    const int a0 = wv * 8;
    for (int base = bid * EPB; base < M; base += GRID * EPB) {
      const int nedge = min(EPB, M - base);
#pragma unroll
      for (int t = 0; t < 8; ++t) {
        int m = base + a0 + t;
        const bool valid = m < M;
        m = valid ? m : M - 1;
        const int p = edges[m];
        const int i = p >> 10, j = p & 1023;
        float h = U1[(i << 6) + lane] + V1[(j << 6) + lane];
        float g = 0.0f;
        const float4* ep = (const float4*)(e + ((size_t)i * NN + j) * DE);
#pragma unroll
        for (int u = 0; u < 8; ++u) {
          float4 f = ep[u];
          h = fmaf(f.x, w1e[4 * u + 0], h);
          h = fmaf(f.y, w1e[4 * u + 1], h);
          h = fmaf(f.z, w1e[4 * u + 2], h);
          h = fmaf(f.w, w1e[4 * u + 3], h);
          g = fmaf(f.x, w2e[4 * u + 0], g);
          g = fmaf(f.y, w2e[4 * u + 1], g);
          g = fmaf(f.z, w2e[4 * u + 2], g);
          g = fmaf(f.w, w2e[4 * u + 3], g);
        }
        sh1b[(a0 + t) * SH1S + lane] = f2b(fmaxf(h, 0.0f));
        if (valid) ew2[(size_t)m * HH + lane] = g;
        if (lane == 0) si[a0 + t] = i;
      }
      __syncthreads();
      phaseB_mfma(sh1b, si, Wbp1, b1b, x1, lane, wv, nedge);
      __syncthreads();
    }
  }
  __threadfence();
  grid.sync();

  // ========== phase 2: U2/V2 from x1 ==========
  for (int r4 = bid; r4 < NN / 4; r4 += GRID) {
    const int rr = tid >> 6, c = tid & 63;
    const int r = r4 * 4 + rr;
    __syncthreads();
    su[rr][c] = x1[r * 64 + c];
    __syncthreads();
    float u = b2a[c], v = 0.0f;
#pragma unroll
    for (int d = 0; d < 64; ++d) {
      float xv = su[rr][d];
      float wxi = W2a[d * 64 + c];
      float wxj = W2a[(64 + d) * 64 + c];
      u = fmaf(xv, wxi - wxj, u);
      v = fmaf(xv, wxj, v);
    }
    U2[r * 64 + c] = u;
    V2[r * 64 + c] = v;
  }
  __threadfence();
  grid.sync();

  // ========== phase 3: conv2 (e-part = ew2, sequential) ==========
  {
    const int a0 = wv * 8;
    for (int base = bid * EPB; base < M; base += GRID * EPB) {
      const int nedge = min(EPB, M - base);
#pragma unroll
      for (int t = 0; t < 8; ++t) {
        int m = base + a0 + t;
        m = m < M ? m : M - 1;
        const int p = edges[m];
        const int i = p >> 10, j = p & 1023;
        const float h = U2[(i << 6) + lane] + V2[(j << 6) + lane]
                      + ew2[(size_t)m * HH + lane];
        sh1b[(a0 + t) * SH1S + lane] = f2b(fmaxf(h, 0.0f));
        if (lane == 0) si[a0 + t] = i;
      }
      __syncthreads();
      phaseB_mfma(sh1b, si, Wbp2, b2b, x2, lane, wv, nedge);
      __syncthreads();
    }
  }
  __threadfence();
  grid.sync();

  // ========== phase 4: head (grid-stride, 2 rows per block-iter) ==========
  for (int i0 = bid * 2; i0 < NN; i0 += GRID * 2) {
    const int half = tid >> 7;
    const int t128 = tid & 127;
    const int i = i0 + half;
    __syncthreads();
    if (t128 < 64) su[half * 2][t128] = x2[i * 64 + t128];
    __syncthreads();
    float p = b3[t128];
#pragma unroll
    for (int c = 0; c < 64; ++c) p = fmaf(su[half * 2][c], W3[c * 128 + t128], p);
    p = fmaxf(p, 0.0f);
    float v = p * W4[t128];
    v += __shfl_down(v, 32);
    v += __shfl_down(v, 16);
    v += __shfl_down(v, 8);
    v += __shfl_down(v, 4);
    v += __shfl_down(v, 2);
    v += __shfl_down(v, 1);
    if (lane == 0) sred[wv] = v;
    __syncthreads();
    if (t128 == 0) {
      float z = sred[half * 2] + sred[half * 2 + 1] + b4[0];
      out[i] = 1.0f / (1.0f + expf(-z));
    }
  }
}

// ============================ fallback path (r8) ============================
__global__ __launch_bounds__(256) void scan_uv_kernel(
    const float* __restrict__ A, const float* __restrict__ x,
    const float* __restrict__ W, const float* __restrict__ bias,
    const float* __restrict__ Wb1, const float* __restrict__ Wb2,
    int* __restrict__ gcnt, int* __restrict__ edges,
    float* __restrict__ U, float* __restrict__ V,
    float* __restrict__ x1, float* __restrict__ x2,
    short* __restrict__ Wbp1, short* __restrict__ Wbp2)
{
  const int i = blockIdx.x;
  const int tid = threadIdx.x;
  __shared__ int s_cnt, s_base;
  __shared__ int s_j[NN];
  __shared__ float sx[64];
  __shared__ float su[4][64], sv[4][64];

  if (tid == 0) s_cnt = 0;
  __syncthreads();
  if (tid < 64) sx[tid] = x[i * 64 + tid];
  for (int j = tid; j < NN; j += 256) {
    if (A[i * NN + j] != 0.0f) {
      int p = atomicAdd(&s_cnt, 1);
      s_j[p] = j;
    }
  }
  if (tid < 64) { x1[i * 64 + tid] = 0.0f; x2[i * 64 + tid] = 0.0f; }

  if (i < 2) {
    const float* src = (i == 0) ? Wb1 : Wb2;
    short* dst = (i == 0) ? Wbp1 : Wbp2;
    for (int L = tid; L < 4096; L += 256) {
      const int j = L & 7, n = (L >> 3) & 15, quad = (L >> 7) & 3;
      const int kb = (L >> 9) & 1, ct = L >> 10;
      dst[L] = f2b(src[(kb * 32 + quad * 8 + j) * 64 + ct * 16 + n]);
    }
  }
  __syncthreads();

  {
    const int c = tid & 63, qr = tid >> 6;
    float u = 0.0f, v = 0.0f;
#pragma unroll
    for (int t = 0; t < 16; ++t) {
      const int d = qr * 16 + t;
      const float xv = sx[d];
      const float wxi = W[d * 64 + c];
      const float wxj = W[(64 + d) * 64 + c];
      u = fmaf(xv, wxi - wxj, u);
      v = fmaf(xv, wxj, v);
    }
    su[qr][c] = u; sv[qr][c] = v;
  }
  if (tid == 0) s_base = atomicAdd(gcnt, s_cnt);
  __syncthreads();

  if (tid < 64) {
    U[i * 64 + tid] = su[0][tid] + su[1][tid] + su[2][tid] + su[3][tid] + bias[tid];
    V[i * 64 + tid] = sv[0][tid] + sv[1][tid] + sv[2][tid] + sv[3][tid];
  }
  const int c = s_cnt, b = s_base;
  for (int t = tid; t < c; t += 256) edges[b + t] = (i << 10) | s_j[t];
}

__global__ __launch_bounds__(256, 4) void uv_kernel(
    const float* __restrict__ x, const float* __restrict__ W,
    const float* __restrict__ bias, float* __restrict__ U, float* __restrict__ V)
{
  const int tid = threadIdx.x;
  const int rr = tid >> 6, c = tid & 63;
  const int r = blockIdx.x * 4 + rr;
  __shared__ float sx[4][64];
  sx[rr][c] = x[r * 64 + c];
  __syncthreads();
  float u = bias[c], v = 0.0f;
#pragma unroll
  for (int d = 0; d < 64; ++d) {
    float xv = sx[rr][d];
    float wxi = W[d * 64 + c];
    float wxj = W[(64 + d) * 64 + c];
    u = fmaf(xv, wxi - wxj, u);
    v = fmaf(xv, wxj, v);
  }
  U[r * 64 + c] = u;
  V[r * 64 + c] = v;
}

__global__ void conv1_kernel(
    const int* __restrict__ gcnt, const int* __restrict__ edges,
    const float* __restrict__ U, const float* __restrict__ V,
    const float* __restrict__ e, const float* __restrict__ We1,
    const float* __restrict__ We2, const short* __restrict__ Wbp,
    const float* __restrict__ bb, float* __restrict__ xout,
    float* __restrict__ ew2)
{
  const int tid = threadIdx.x, lane = tid & 63, wv = tid >> 6;
  const int M = gcnt[0];
  const int base = blockIdx.x * EPB;
  if (base >= M) return;
  const int nedge = min(EPB, M - base);

  __shared__ __align__(16) short sh1b[EPB * SH1S];
  __shared__ int si[EPB];

  float w1e[DE], w2e[DE];
#pragma unroll
  for (int d = 0; d < DE; ++d) { w1e[d] = We1[d * HH + lane]; w2e[d] = We2[d * HH + lane]; }

  const int a0 = wv * 8;
#pragma unroll
  for (int t = 0; t < 8; ++t) {
    int m = base + a0 + t;
    const bool valid = m < M;
    m = valid ? m : M - 1;
    const int p = edges[m];
    const int i = p >> 10, j = p & 1023;
    float h = U[(i << 6) + lane] + V[(j << 6) + lane];
    float g = 0.0f;
    const float4* ep = (const float4*)(e + ((size_t)i * NN + j) * DE);
#pragma unroll
    for (int u = 0; u < 8; ++u) {
      float4 f = ep[u];
      h = fmaf(f.x, w1e[4 * u + 0], h);
      h = fmaf(f.y, w1e[4 * u + 1], h);
      h = fmaf(f.z, w1e[4 * u + 2], h);
      h = fmaf(f.w, w1e[4 * u + 3], h);
      g = fmaf(f.x, w2e[4 * u + 0], g);
      g = fmaf(f.y, w2e[4 * u + 1], g);
      g = fmaf(f.z, w2e[4 * u + 2], g);
      g = fmaf(f.w, w2e[4 * u + 3], g);
    }
    sh1b[(a0 + t) * SH1S + lane] = f2b(fmaxf(h, 0.0f));
    if (valid) ew2[(size_t)m * HH + lane] = g;
    if (lane == 0) si[a0 + t] = i;
  }
  __syncthreads();
  phaseB_mfma(sh1b, si, Wbp, bb, xout, lane, wv, nedge);
}

__global__ void conv2_kernel(
    const int* __restrict__ gcnt, const int* __restrict__ edges,
    const float* __restrict__ U, const float* __restrict__ V,
    const float* __restrict__ ew2, const short* __restrict__ Wbp,
    const float* __restrict__ bb, float* __restrict__ xout)
{
  const int tid = threadIdx.x, lane = tid & 63, wv = tid >> 6;
  const int M = gcnt[0];
  const int base = blockIdx.x * EPB;
  if (base >= M) return;
  const int nedge = min(EPB, M - base);

  __shared__ __align__(16) short sh1b[EPB * SH1S];
  __shared__ int si[EPB];

  const int a0 = wv * 8;
#pragma unroll
  for (int t = 0; t < 8; ++t) {
    int m = base + a0 + t;
    m = m < M ? m : M - 1;
    const int p = edges[m];
    const int i = p >> 10, j = p & 1023;
    const float h = U[(i << 6) + lane] + V[(j << 6) + lane]
                  + ew2[(size_t)m * HH + lane];
    sh1b[(a0 + t) * SH1S + lane] = f2b(fmaxf(h, 0.0f));
    if (lane == 0) si[a0 + t] = i;
  }
  __syncthreads();
  phaseB_mfma(sh1b, si, Wbp, bb, xout, lane, wv, nedge);
}

__global__ __launch_bounds__(128) void final_kernel(
    const float* __restrict__ x2, const float* __restrict__ W3,
    const float* __restrict__ b3, const float* __restrict__ W4,
    const float* __restrict__ b4, float* __restrict__ out)
{
  const int i = blockIdx.x;
  const int t = threadIdx.x;
  const int lane = t & 63;
  const int wv = t >> 6;
  __shared__ float sx[64];
  __shared__ float s_red[2];
  if (t < 64) sx[t] = x2[i * 64 + t];
  __syncthreads();
  float p = b3[t];
#pragma unroll
  for (int c = 0; c < 64; ++c) p = fmaf(sx[c], W3[c * 128 + t], p);
  p = fmaxf(p, 0.0f);
  float v = p * W4[t];
  v += __shfl_down(v, 32);
  v += __shfl_down(v, 16);
  v += __shfl_down(v, 8);
  v += __shfl_down(v, 4);
  v += __shfl_down(v, 2);
  v += __shfl_down(v, 1);
  if (lane == 0) s_red[wv] = v;
  __syncthreads();
  if (t == 0) {
    float z = s_red[0] + s_red[1] + b4[0];
    out[i] = 1.0f / (1.0f + expf(-z));
  }
}

extern "C" void kernel_launch(void* const* d_in, const int* in_sizes, int n_in,
                              void* d_out, int out_size, void* d_ws, size_t ws_size,
                              hipStream_t stream) {
  const float* A   = (const float*)d_in[0];
  const float* x   = (const float*)d_in[1];
  const float* e   = (const float*)d_in[2];
  const float* W1a = (const float*)d_in[3];
  const float* b1a = (const float*)d_in[4];
  const float* W1b = (const float*)d_in[5];
  const float* b1b = (const float*)d_in[6];
  const float* W2a = (const float*)d_in[7];
  const float* b2a = (const float*)d_in[8];
  const float* W2b = (const float*)d_in[9];
  const float* b2b = (const float*)d_in[10];
  const float* W3  = (const float*)d_in[11];
  const float* b3  = (const float*)d_in[12];
  const float* W4  = (const float*)d_in[13];
  const float* b4  = (const float*)d_in[14];
  float* out = (float*)d_out;

  // ws: [gcnt(16i) | x1 | x2 | U1 | V1 | U2 | V2 | edges | ew2 | Wbp1 | Wbp2]
  int*   gcnt  = (int*)d_ws;
  float* x1    = (float*)d_ws + 16;
  float* x2    = x1 + NN * HH;
  float* U1    = x2 + NN * HH;
  float* V1    = U1 + NN * HH;
  float* U2    = V1 + NN * HH;
  float* V2    = U2 + NN * HH;
  int*   edges = (int*)(V2 + NN * HH);
  float* ew2   = (float*)(edges + ECAP);
  short* Wbp1  = (short*)(ew2 + (size_t)ECAP * HH);
  short* Wbp2  = Wbp1 + 4096;

  hipMemsetAsync(gcnt, 0, 16 * sizeof(int), stream);

  void* args[] = {
    (void*)&A, (void*)&x, (void*)&e,
    (void*)&W1a, (void*)&b1a, (void*)&W1b, (void*)&b1b,
    (void*)&W2a, (void*)&b2a, (void*)&W2b, (void*)&b2b,
    (void*)&W3, (void*)&b3, (void*)&W4, (void*)&b4,
    (void*)&out,
    (void*)&gcnt, (void*)&edges, (void*)&x1, (void*)&x2,
    (void*)&U1, (void*)&V1, (void*)&U2, (void*)&V2,
    (void*)&ew2, (void*)&Wbp1, (void*)&Wbp2,
  };
  hipError_t err = hipLaunchCooperativeKernel((void*)mega_kernel, dim3(GRID),
                                              dim3(256), args, 0, stream);
  if (err != hipSuccess) {
    // fallback: proven r8 five-kernel path (identical math)
    scan_uv_kernel<<<NN, 256, 0, stream>>>(A, x, W1a, b1a, W1b, W2b,
                                           gcnt, edges, U1, V1, x1, x2, Wbp1, Wbp2);
    conv1_kernel<<<CGRID, 256, 0, stream>>>(gcnt, edges, U1, V1, e,
                                            W1a + 128 * HH, W2a + 128 * HH,
                                            Wbp1, b1b, x1, ew2);
    uv_kernel<<<NN / 4, 256, 0, stream>>>(x1, W2a, b2a, U2, V2);
    conv2_kernel<<<CGRID, 256, 0, stream>>>(gcnt, edges, U2, V2, ew2,
                                            Wbp2, b2b, x2);
    final_kernel<<<NN, 128, 0, stream>>>(x2, W3, b3, W4, b4, out);
  }
}

// Round 11
// 188.883 us; speedup vs baseline: 2.2497x; 2.2497x over previous
//
#include <hip/hip_runtime.h>
#include <math.h>

// Sparse EdgeConvE round 11: latency-hiding via many small blocks.
//   h1 = relu( U[i] + V[j] + e_ij @ We ),  U = x@(Wxi-Wxj)+ba, V = x@Wxj
//   out[i] = sum_j relu( h1 @ Wb + bb )
// Block = (node i, chunk of 16 edges): grid 768*8=6144 (~2150 active),
// 2.3 KB LDS, phase B = 2 MFMA per wave on a 16x64 tile, 1 atomic/wave.
// Row-indexed edge lists (cnt/jl) -> no global atomic, no memset dispatch.
// conv1 also emits ew2[(i,slot)] = e_ij @ We2 so conv2 has no e gather.

#define NN 768
#define FF 64
#define DE 32
#define HH 64
#define EPB 16             // edges per conv block
#define MAXB 8             // chunks per node (CAP/EPB)
#define CAP 128            // per-row edge capacity (deg ~38 +- 6; 15 sigma)
#define SH1S 72            // padded bf16 row stride (16B-aligned reads, 2-way banks)

using bf16x8 = __attribute__((ext_vector_type(8))) short;
using f32x4  = __attribute__((ext_vector_type(4))) float;

__device__ __forceinline__ short f2b(float f) {
  unsigned u = __float_as_uint(f);
  return (short)((u + 0x7fffu + ((u >> 16) & 1u)) >> 16);   // RNE
}

// ---- scan row -> cnt/jl; U1/V1; zero x1/x2; blocks 0/1 pack Wb (bf16 B-frag)
__global__ __launch_bounds__(256) void scan_uv_kernel(
    const float* __restrict__ A, const float* __restrict__ x,
    const float* __restrict__ W, const float* __restrict__ bias,
    const float* __restrict__ Wb1, const float* __restrict__ Wb2,
    int* __restrict__ cnt, int* __restrict__ jl,
    float* __restrict__ U, float* __restrict__ V,
    float* __restrict__ x1, float* __restrict__ x2,
    short* __restrict__ Wbp1, short* __restrict__ Wbp2)
{
  const int i = blockIdx.x;
  const int tid = threadIdx.x;
  __shared__ int s_cnt;
  __shared__ int s_j[NN];
  __shared__ float sx[64];
  __shared__ float su[4][64], sv[4][64];

  if (tid == 0) s_cnt = 0;
  __syncthreads();
  if (tid < 64) sx[tid] = x[i * 64 + tid];
  if (tid < NN / 4) {          // 192 threads scan the row as float4
    float4 a = ((const float4*)(A + i * NN))[tid];
    if (a.x != 0.0f) { int p = atomicAdd(&s_cnt, 1); s_j[p] = tid * 4 + 0; }
    if (a.y != 0.0f) { int p = atomicAdd(&s_cnt, 1); s_j[p] = tid * 4 + 1; }
    if (a.z != 0.0f) { int p = atomicAdd(&s_cnt, 1); s_j[p] = tid * 4 + 2; }
    if (a.w != 0.0f) { int p = atomicAdd(&s_cnt, 1); s_j[p] = tid * 4 + 3; }
  }
  if (tid < 64) { x1[i * 64 + tid] = 0.0f; x2[i * 64 + tid] = 0.0f; }

  if (i < 2) {  // pack Wb into bf16 B-fragment order
    const float* src = (i == 0) ? Wb1 : Wb2;
    short* dst = (i == 0) ? Wbp1 : Wbp2;
    for (int L = tid; L < 4096; L += 256) {
      const int j = L & 7, n = (L >> 3) & 15, quad = (L >> 7) & 3;
      const int kb = (L >> 9) & 1, ct = L >> 10;
      dst[L] = f2b(src[(kb * 32 + quad * 8 + j) * 64 + ct * 16 + n]);
    }
  }
  __syncthreads();

  {  // U/V: c = tid&63, K-quarter = tid>>6
    const int c = tid & 63, qr = tid >> 6;
    float u = 0.0f, v = 0.0f;
#pragma unroll
    for (int t = 0; t < 16; ++t) {
      const int d = qr * 16 + t;
      const float xv = sx[d];
      const float wxi = W[d * 64 + c];
      const float wxj = W[(64 + d) * 64 + c];
      u = fmaf(xv, wxi - wxj, u);
      v = fmaf(xv, wxj, v);
    }
    su[qr][c] = u; sv[qr][c] = v;
  }
  __syncthreads();

  if (tid < 64) {
    U[i * 64 + tid] = su[0][tid] + su[1][tid] + su[2][tid] + su[3][tid] + bias[tid];
    V[i * 64 + tid] = sv[0][tid] + sv[1][tid] + sv[2][tid] + sv[3][tid];
  }
  const int c = min(s_cnt, CAP);
  if (tid == 0) cnt[i] = c;
  for (int t = tid; t < c; t += 256) jl[(i << 7) + t] = s_j[t];
}

// ---- U2/V2 from x1
__global__ __launch_bounds__(256, 4) void uv_kernel(
    const float* __restrict__ x, const float* __restrict__ W,
    const float* __restrict__ bias, float* __restrict__ U, float* __restrict__ V)
{
  const int tid = threadIdx.x;
  const int rr = tid >> 6, c = tid & 63;
  const int r = blockIdx.x * 4 + rr;
  __shared__ float sx[4][64];
  sx[rr][c] = x[r * 64 + c];
  __syncthreads();
  float u = bias[c], v = 0.0f;
#pragma unroll
  for (int d = 0; d < 64; ++d) {
    float xv = sx[rr][d];
    float wxi = W[d * 64 + c];
    float wxj = W[(64 + d) * 64 + c];
    u = fmaf(xv, wxi - wxj, u);
    v = fmaf(xv, wxj, v);
  }
  U[r * 64 + c] = u;
  V[r * 64 + c] = v;
}

// ---- phase B: H1[16x64]bf16 @ Wb -> 16x16 tile per wave (ct = wv),
// sum rows (edges) with relu+bias, one atomicAdd per wave.
__device__ __forceinline__ void phaseB16(
    const short* sh1b, const short* __restrict__ Wbp,
    const float* __restrict__ bb, float* __restrict__ xout,
    int i, int lane, int wv, int nedge)
{
  const int q = lane >> 4, n = lane & 15;
  bf16x8 b0 = *(const bf16x8*)(Wbp + (((wv * 2 + 0) * 4 + q) * 16 + n) * 8);
  bf16x8 b1 = *(const bf16x8*)(Wbp + (((wv * 2 + 1) * 4 + q) * 16 + n) * 8);
  const float bias = bb[wv * 16 + n];
  const short* sa = sh1b + n * SH1S + q * 8;
  bf16x8 a0 = *(const bf16x8*)(sa);
  bf16x8 a1 = *(const bf16x8*)(sa + 32);

  f32x4 acc = {0.f, 0.f, 0.f, 0.f};
  acc = __builtin_amdgcn_mfma_f32_16x16x32_bf16(a0, b0, acc, 0, 0, 0);
  acc = __builtin_amdgcn_mfma_f32_16x16x32_bf16(a1, b1, acc, 0, 0, 0);

  float s = 0.0f;
#pragma unroll
  for (int reg = 0; reg < 4; ++reg) {
    const int row = q * 4 + reg;                 // edge slot
    const float v = fmaxf(acc[reg] + bias, 0.0f);
    s += (row < nedge) ? v : 0.0f;
  }
  s += __shfl_down(s, 32);
  s += __shfl_down(s, 16);
  if (lane < 16) atomicAdd(&xout[(i << 6) + wv * 16 + lane], s);
}

// ---- conv1: phase A fp32 (e gather) + ew2 side product, phase B MFMA
__global__ __launch_bounds__(256) void conv1_kernel(
    const int* __restrict__ cnt, const int* __restrict__ jl,
    const float* __restrict__ U, const float* __restrict__ V,
    const float* __restrict__ e, const float* __restrict__ We1,
    const float* __restrict__ We2, const short* __restrict__ Wbp,
    const float* __restrict__ bb, float* __restrict__ xout,
    float* __restrict__ ew2)
{
  const int i = blockIdx.x >> 3;
  const int t0 = (blockIdx.x & (MAXB - 1)) * EPB;
  const int c = cnt[i];
  if (t0 >= c) return;
  const int nedge = min(EPB, c - t0);

  const int tid = threadIdx.x, lane = tid & 63, wv = tid >> 6;
  __shared__ __align__(16) short sh1b[EPB * SH1S];

  float w1e[DE], w2e[DE];
#pragma unroll
  for (int d = 0; d < DE; ++d) { w1e[d] = We1[d * HH + lane]; w2e[d] = We2[d * HH + lane]; }

  const float u_i = U[(i << 6) + lane];
#pragma unroll
  for (int t = 0; t < 4; ++t) {
    const int slot = wv * 4 + t;
    const int idx = t0 + (slot < nedge ? slot : nedge - 1);
    const int j = jl[(i << 7) + idx];
    float h = u_i + V[(j << 6) + lane];
    float g = 0.0f;
    const float4* ep = (const float4*)(e + ((size_t)(i * NN + j)) * DE);
#pragma unroll
    for (int u = 0; u < 8; ++u) {
      float4 f = ep[u];                 // wave-uniform address -> broadcast
      h = fmaf(f.x, w1e[4 * u + 0], h);
      h = fmaf(f.y, w1e[4 * u + 1], h);
      h = fmaf(f.z, w1e[4 * u + 2], h);
      h = fmaf(f.w, w1e[4 * u + 3], h);
      g = fmaf(f.x, w2e[4 * u + 0], g);
      g = fmaf(f.y, w2e[4 * u + 1], g);
      g = fmaf(f.z, w2e[4 * u + 2], g);
      g = fmaf(f.w, w2e[4 * u + 3], g);
    }
    sh1b[slot * SH1S + lane] = f2b(fmaxf(h, 0.0f));
    if (slot < nedge) ew2[((size_t)(i << 7) + t0 + slot) * HH + lane] = g;
  }
  __syncthreads();
  phaseB16(sh1b, Wbp, bb, xout, i, lane, wv, nedge);
}

// ---- conv2: e-part precomputed in ew2 (no random gather)
__global__ __launch_bounds__(256) void conv2_kernel(
    const int* __restrict__ cnt, const int* __restrict__ jl,
    const float* __restrict__ U, const float* __restrict__ V,
    const float* __restrict__ ew2, const short* __restrict__ Wbp,
    const float* __restrict__ bb, float* __restrict__ xout)
{
  const int i = blockIdx.x >> 3;
  const int t0 = (blockIdx.x & (MAXB - 1)) * EPB;
  const int c = cnt[i];
  if (t0 >= c) return;
  const int nedge = min(EPB, c - t0);

  const int tid = threadIdx.x, lane = tid & 63, wv = tid >> 6;
  __shared__ __align__(16) short sh1b[EPB * SH1S];

  const float u_i = U[(i << 6) + lane];
#pragma unroll
  for (int t = 0; t < 4; ++t) {
    const int slot = wv * 4 + t;
    const int idx = t0 + (slot < nedge ? slot : nedge - 1);
    const int j = jl[(i << 7) + idx];
    const float h = u_i + V[(j << 6) + lane]
                  + ew2[((size_t)(i << 7) + idx) * HH + lane];
    sh1b[slot * SH1S + lane] = f2b(fmaxf(h, 0.0f));
  }
  __syncthreads();
  phaseB16(sh1b, Wbp, bb, xout, i, lane, wv, nedge);
}

// ---- head: x2 -> relu(@W3+b3) -> sigmoid(@W4+b4)
__global__ __launch_bounds__(128) void final_kernel(
    const float* __restrict__ x2, const float* __restrict__ W3,
    const float* __restrict__ b3, const float* __restrict__ W4,
    const float* __restrict__ b4, float* __restrict__ out)
{
  const int i = blockIdx.x;
  const int t = threadIdx.x;
  const int lane = t & 63;
  const int wv = t >> 6;
  __shared__ float sx[64];
  __shared__ float s_red[2];
  if (t < 64) sx[t] = x2[i * 64 + t];
  __syncthreads();
  float p = b3[t];
#pragma unroll
  for (int c = 0; c < 64; ++c) p = fmaf(sx[c], W3[c * 128 + t], p);
  p = fmaxf(p, 0.0f);
  float v = p * W4[t];
  v += __shfl_down(v, 32);
  v += __shfl_down(v, 16);
  v += __shfl_down(v, 8);
  v += __shfl_down(v, 4);
  v += __shfl_down(v, 2);
  v += __shfl_down(v, 1);
  if (lane == 0) s_red[wv] = v;
  __syncthreads();
  if (t == 0) {
    float z = s_red[0] + s_red[1] + b4[0];
    out[i] = 1.0f / (1.0f + expf(-z));
  }
}

extern "C" void kernel_launch(void* const* d_in, const int* in_sizes, int n_in,
                              void* d_out, int out_size, void* d_ws, size_t ws_size,
                              hipStream_t stream) {
  const float* A   = (const float*)d_in[0];
  const float* x   = (const float*)d_in[1];
  const float* e   = (const float*)d_in[2];
  const float* W1a = (const float*)d_in[3];
  const float* b1a = (const float*)d_in[4];
  const float* W1b = (const float*)d_in[5];
  const float* b1b = (const float*)d_in[6];
  const float* W2a = (const float*)d_in[7];
  const float* b2a = (const float*)d_in[8];
  const float* W2b = (const float*)d_in[9];
  const float* b2b = (const float*)d_in[10];
  const float* W3  = (const float*)d_in[11];
  const float* b3  = (const float*)d_in[12];
  const float* W4  = (const float*)d_in[13];
  const float* b4  = (const float*)d_in[14];
  float* out = (float*)d_out;

  // ws: [cnt(768i) | jl(768*128 i) | x1 | x2 | U1 | V1 | U2 | V2 | ew2 | Wbp1 | Wbp2]
  int*   cnt  = (int*)d_ws;
  int*   jl   = cnt + NN;
  float* x1   = (float*)(jl + NN * CAP);
  float* x2   = x1 + NN * HH;
  float* U1   = x2 + NN * HH;
  float* V1   = U1 + NN * HH;
  float* U2   = V1 + NN * HH;
  float* V2   = U2 + NN * HH;
  float* ew2  = V2 + NN * HH;                       // 768*128*64 floats
  short* Wbp1 = (short*)(ew2 + (size_t)NN * CAP * HH);
  short* Wbp2 = Wbp1 + 4096;

  scan_uv_kernel<<<NN, 256, 0, stream>>>(A, x, W1a, b1a, W1b, W2b,
                                         cnt, jl, U1, V1, x1, x2, Wbp1, Wbp2);
  conv1_kernel<<<NN * MAXB, 256, 0, stream>>>(cnt, jl, U1, V1, e,
                                              W1a + 128 * HH, W2a + 128 * HH,
                                              Wbp1, b1b, x1, ew2);
  uv_kernel<<<NN / 4, 256, 0, stream>>>(x1, W2a, b2a, U2, V2);
  conv2_kernel<<<NN * MAXB, 256, 0, stream>>>(cnt, jl, U2, V2, ew2,
                                              Wbp2, b2b, x2);
  final_kernel<<<NN, 128, 0, stream>>>(x2, W3, b3, W4, b4, out);
}

// Round 12
// 162.346 us; speedup vs baseline: 2.6174x; 1.1635x over previous
//
#include <hip/hip_runtime.h>
#include <math.h>

// Sparse EdgeConvE round 12: minimize dependent-miss chain depth.
//   h1 = relu( U[i] + V[j] + e_ij @ We ),  U = x@(Wxi-Wxj)+ba, V = x@Wxj
//   out[i] = sum_j relu( h1 @ Wb + bb )
// scan_kernel: row scan -> s_j (LDS) -> gather e rows (depth 2) -> compute
//   ew1/ew2 = e@We{1,2} in-block -> sequential stores; also U1/V1, Wb pack.
// conv_kernel (used for BOTH layers): h1 = U[i]+V[j]+ew[i,slot] (depth 1),
//   bf16 MFMA phase B, plain partial stores xp[(i,chunk)] (no atomics).
// uv2/final: sum <=8 partials on read (sequential), then as before.

#define NN 768
#define FF 64
#define DE 32
#define HH 64
#define EPB 16             // edges per conv chunk
#define MAXB 8             // chunks per node (CAP/EPB)
#define CAP 128            // per-row edge capacity (deg ~38 +- 6)
#define SH1S 72            // padded bf16 LDS row stride

using bf16x8 = __attribute__((ext_vector_type(8))) short;
using f32x4  = __attribute__((ext_vector_type(4))) float;

__device__ __forceinline__ short f2b(float f) {
  unsigned u = __float_as_uint(f);
  return (short)((u + 0x7fffu + ((u >> 16) & 1u)) >> 16);   // RNE
}

// ---- scan + e-gather + ew1/ew2 + U1/V1 + Wb pack ----
__global__ __launch_bounds__(256) void scan_kernel(
    const float* __restrict__ A, const float* __restrict__ x,
    const float* __restrict__ e,
    const float* __restrict__ W, const float* __restrict__ bias,   // W1a,b1a
    const float* __restrict__ We1, const float* __restrict__ We2,
    const float* __restrict__ Wb1, const float* __restrict__ Wb2,
    int* __restrict__ cnt, int* __restrict__ jl,
    float* __restrict__ U, float* __restrict__ V,
    float* __restrict__ ew1, float* __restrict__ ew2,
    short* __restrict__ Wbp1, short* __restrict__ Wbp2)
{
  const int i = blockIdx.x;
  const int tid = threadIdx.x;
  __shared__ int s_cnt;
  __shared__ int s_j[CAP];
  __shared__ float sx[64];
  __shared__ float su[4][64], sv[4][64];
  __shared__ __align__(16) float es[CAP][DE];   // 16 KB gathered e rows

  if (tid == 0) s_cnt = 0;
  __syncthreads();
  if (tid < 64) sx[tid] = x[i * 64 + tid];
  if (tid < NN / 4) {
    float4 a = ((const float4*)(A + i * NN))[tid];
    if (a.x != 0.0f) { int p = atomicAdd(&s_cnt, 1); if (p < CAP) s_j[p] = tid * 4 + 0; }
    if (a.y != 0.0f) { int p = atomicAdd(&s_cnt, 1); if (p < CAP) s_j[p] = tid * 4 + 1; }
    if (a.z != 0.0f) { int p = atomicAdd(&s_cnt, 1); if (p < CAP) s_j[p] = tid * 4 + 2; }
    if (a.w != 0.0f) { int p = atomicAdd(&s_cnt, 1); if (p < CAP) s_j[p] = tid * 4 + 3; }
  }
  __syncthreads();
  const int c = min(s_cnt, CAP);

  // gather e rows into LDS: 8 threads per slot (128 B each), all parallel
  for (int slot = tid >> 3; slot < c; slot += 32) {
    const int j = s_j[slot];
    ((float4*)es[slot])[tid & 7] =
        ((const float4*)(e + ((size_t)i * NN + j) * DE))[tid & 7];
  }

  const int c64 = tid & 63, sg = tid >> 6;
  // per-thread e-weights for channel c64 (both layers)
  float w1[DE], w2[DE];
#pragma unroll
  for (int d = 0; d < DE; ++d) { w1[d] = We1[d * HH + c64]; w2[d] = We2[d * HH + c64]; }
  __syncthreads();

  // ew1/ew2 for this row's edges; stores are coalesced over c64
  for (int slot = sg; slot < c; slot += 4) {
    float a1 = 0.0f, a2 = 0.0f;
#pragma unroll
    for (int d = 0; d < DE; ++d) {
      const float f = es[slot][d];        // wave-uniform LDS broadcast
      a1 = fmaf(f, w1[d], a1);
      a2 = fmaf(f, w2[d], a2);
    }
    ew1[((size_t)(i << 7) + slot) * HH + c64] = a1;
    ew2[((size_t)(i << 7) + slot) * HH + c64] = a2;
  }

  // U1/V1 partials (qr = sg)
  {
    float u = 0.0f, v = 0.0f;
#pragma unroll
    for (int t = 0; t < 16; ++t) {
      const int d = sg * 16 + t;
      const float xv = sx[d];
      const float wxi = W[d * 64 + c64];
      const float wxj = W[(64 + d) * 64 + c64];
      u = fmaf(xv, wxi - wxj, u);
      v = fmaf(xv, wxj, v);
    }
    su[sg][c64] = u; sv[sg][c64] = v;
  }

  if (i < 2) {  // pack Wb into bf16 B-fragment order
    const float* src = (i == 0) ? Wb1 : Wb2;
    short* dst = (i == 0) ? Wbp1 : Wbp2;
    for (int L = tid; L < 4096; L += 256) {
      const int j = L & 7, n = (L >> 3) & 15, quad = (L >> 7) & 3;
      const int kb = (L >> 9) & 1, ct = L >> 10;
      dst[L] = f2b(src[(kb * 32 + quad * 8 + j) * 64 + ct * 16 + n]);
    }
  }
  __syncthreads();

  if (tid < 64) {
    U[i * 64 + tid] = su[0][tid] + su[1][tid] + su[2][tid] + su[3][tid] + bias[tid];
    V[i * 64 + tid] = sv[0][tid] + sv[1][tid] + sv[2][tid] + sv[3][tid];
  }
  if (tid == 0) cnt[i] = c;
  for (int t = tid; t < c; t += 256) jl[(i << 7) + t] = s_j[t];
}

// ---- conv (both layers): depth-1 phase A, MFMA phase B, partial stores ----
__global__ __launch_bounds__(256) void conv_kernel(
    const int* __restrict__ cnt, const int* __restrict__ jl,
    const float* __restrict__ U, const float* __restrict__ V,
    const float* __restrict__ ew, const short* __restrict__ Wbp,
    const float* __restrict__ bb, float* __restrict__ xp)
{
  const int i = blockIdx.x >> 3;
  const int chunk = blockIdx.x & (MAXB - 1);
  const int t0 = chunk * EPB;
  const int c = cnt[i];
  if (t0 >= c) return;
  const int nedge = min(EPB, c - t0);

  const int tid = threadIdx.x, lane = tid & 63, wv = tid >> 6;
  __shared__ __align__(16) short sh1b[EPB * SH1S];

  const float u_i = U[(i << 6) + lane];
#pragma unroll
  for (int t = 0; t < 4; ++t) {
    const int slot = wv * 4 + t;
    const int idx = t0 + (slot < nedge ? slot : nedge - 1);
    const int j = jl[(i << 7) + idx];
    const float h = u_i + V[(j << 6) + lane]
                  + ew[((size_t)(i << 7) + idx) * HH + lane];
    sh1b[slot * SH1S + lane] = f2b(fmaxf(h, 0.0f));
  }
  __syncthreads();

  // phase B: H1[16x64] @ Wb -> 16 channels per wave (ct = wv)
  const int q = lane >> 4, n = lane & 15;
  bf16x8 b0 = *(const bf16x8*)(Wbp + (((wv * 2 + 0) * 4 + q) * 16 + n) * 8);
  bf16x8 b1 = *(const bf16x8*)(Wbp + (((wv * 2 + 1) * 4 + q) * 16 + n) * 8);
  const float bias = bb[wv * 16 + n];
  const short* sa = sh1b + n * SH1S + q * 8;
  bf16x8 a0 = *(const bf16x8*)(sa);
  bf16x8 a1 = *(const bf16x8*)(sa + 32);

  f32x4 acc = {0.f, 0.f, 0.f, 0.f};
  acc = __builtin_amdgcn_mfma_f32_16x16x32_bf16(a0, b0, acc, 0, 0, 0);
  acc = __builtin_amdgcn_mfma_f32_16x16x32_bf16(a1, b1, acc, 0, 0, 0);

  float s = 0.0f;
#pragma unroll
  for (int reg = 0; reg < 4; ++reg) {
    const int row = q * 4 + reg;
    const float v = fmaxf(acc[reg] + bias, 0.0f);
    s += (row < nedge) ? v : 0.0f;
  }
  s += __shfl_down(s, 32);
  s += __shfl_down(s, 16);
  if (lane < 16)
    xp[(((i << 3) + chunk) << 6) + wv * 16 + lane] = s;   // plain store
}

// ---- U2/V2 from x1 partials (sum <=8 chunks on read) ----
__global__ __launch_bounds__(256, 4) void uv2_kernel(
    const int* __restrict__ cnt, const float* __restrict__ xp,
    const float* __restrict__ W, const float* __restrict__ bias,
    float* __restrict__ U, float* __restrict__ V)
{
  const int tid = threadIdx.x;
  const int rr = tid >> 6, c64 = tid & 63;
  const int r = blockIdx.x * 4 + rr;
  __shared__ float sx[4][64];
  const int nch = (cnt[r] + EPB - 1) / EPB;
  float xv = 0.0f;
  for (int ch = 0; ch < nch; ++ch) xv += xp[(((r << 3) + ch) << 6) + c64];
  sx[rr][c64] = xv;
  __syncthreads();
  float u = bias[c64], v = 0.0f;
#pragma unroll
  for (int d = 0; d < 64; ++d) {
    const float t = sx[rr][d];
    const float wxi = W[d * 64 + c64];
    const float wxj = W[(64 + d) * 64 + c64];
    u = fmaf(t, wxi - wxj, u);
    v = fmaf(t, wxj, v);
  }
  U[r * 64 + c64] = u;
  V[r * 64 + c64] = v;
}

// ---- head: sum x2 partials -> relu(@W3+b3) -> sigmoid(@W4+b4) ----
__global__ __launch_bounds__(128) void final_kernel(
    const int* __restrict__ cnt, const float* __restrict__ xp,
    const float* __restrict__ W3, const float* __restrict__ b3,
    const float* __restrict__ W4, const float* __restrict__ b4,
    float* __restrict__ out)
{
  const int i = blockIdx.x;
  const int t = threadIdx.x;
  const int lane = t & 63;
  const int wv = t >> 6;
  __shared__ float sx[64];
  __shared__ float s_red[2];
  if (t < 64) {
    const int nch = (cnt[i] + EPB - 1) / EPB;
    float xv = 0.0f;
    for (int ch = 0; ch < nch; ++ch) xv += xp[(((i << 3) + ch) << 6) + t];
    sx[t] = xv;
  }
  __syncthreads();
  float p = b3[t];
#pragma unroll
  for (int c = 0; c < 64; ++c) p = fmaf(sx[c], W3[c * 128 + t], p);
  p = fmaxf(p, 0.0f);
  float v = p * W4[t];
  v += __shfl_down(v, 32);
  v += __shfl_down(v, 16);
  v += __shfl_down(v, 8);
  v += __shfl_down(v, 4);
  v += __shfl_down(v, 2);
  v += __shfl_down(v, 1);
  if (lane == 0) s_red[wv] = v;
  __syncthreads();
  if (t == 0) {
    float z = s_red[0] + s_red[1] + b4[0];
    out[i] = 1.0f / (1.0f + expf(-z));
  }
}

extern "C" void kernel_launch(void* const* d_in, const int* in_sizes, int n_in,
                              void* d_out, int out_size, void* d_ws, size_t ws_size,
                              hipStream_t stream) {
  const float* A   = (const float*)d_in[0];
  const float* x   = (const float*)d_in[1];
  const float* e   = (const float*)d_in[2];
  const float* W1a = (const float*)d_in[3];
  const float* b1a = (const float*)d_in[4];
  const float* W1b = (const float*)d_in[5];
  const float* b1b = (const float*)d_in[6];
  const float* W2a = (const float*)d_in[7];
  const float* b2a = (const float*)d_in[8];
  const float* W2b = (const float*)d_in[9];
  const float* b2b = (const float*)d_in[10];
  const float* W3  = (const float*)d_in[11];
  const float* b3  = (const float*)d_in[12];
  const float* W4  = (const float*)d_in[13];
  const float* b4  = (const float*)d_in[14];
  float* out = (float*)d_out;

  // ws: [cnt | jl | U1 V1 U2 V2 | ew1 ew2 | x1p x2p | Wbp1 Wbp2]
  int*   cnt  = (int*)d_ws;
  int*   jl   = cnt + NN;                            // 768*128
  float* U1   = (float*)(jl + NN * CAP);
  float* V1   = U1 + NN * HH;
  float* U2   = V1 + NN * HH;
  float* V2   = U2 + NN * HH;
  float* ew1  = V2 + NN * HH;                        // 768*128*64
  float* ew2  = ew1 + (size_t)NN * CAP * HH;
  float* x1p  = ew2 + (size_t)NN * CAP * HH;         // 768*8*64
  float* x2p  = x1p + NN * MAXB * HH;
  short* Wbp1 = (short*)(x2p + NN * MAXB * HH);
  short* Wbp2 = Wbp1 + 4096;

  scan_kernel<<<NN, 256, 0, stream>>>(A, x, e, W1a, b1a,
                                      W1a + 128 * HH, W2a + 128 * HH,
                                      W1b, W2b,
                                      cnt, jl, U1, V1, ew1, ew2, Wbp1, Wbp2);
  conv_kernel<<<NN * MAXB, 256, 0, stream>>>(cnt, jl, U1, V1, ew1, Wbp1, b1b, x1p);
  uv2_kernel<<<NN / 4, 256, 0, stream>>>(cnt, x1p, W2a, b2a, U2, V2);
  conv_kernel<<<NN * MAXB, 256, 0, stream>>>(cnt, jl, U2, V2, ew2, Wbp2, b2b, x2p);
  final_kernel<<<NN, 128, 0, stream>>>(cnt, x2p, W3, b3, W4, b4, out);
}